// Round 10
// baseline (6274.752 us; speedup 1.0000x reference)
//
#include <hip/hip_runtime.h>
#include <math.h>
#include <stdint.h>

#define TLEN 256
#define NB   32
#define HID  512
#define VOC  1024

typedef __attribute__((ext_vector_type(2))) _Float16 half2_t;
typedef __attribute__((ext_vector_type(2))) __fp16  pk16_t;

// ---- device-coherent (agent-scope) Z accessors ----
__device__ __forceinline__ float zload(const float* p) {
    return __hip_atomic_load(p, __ATOMIC_RELAXED, __HIP_MEMORY_SCOPE_AGENT);
}
__device__ __forceinline__ float2 zload2(const float* p) {
    unsigned long long u = __hip_atomic_load((const unsigned long long*)p,
                                             __ATOMIC_RELAXED, __HIP_MEMORY_SCOPE_AGENT);
    union { unsigned long long u; float2 f; } c; c.u = u; return c.f;
}
__device__ __forceinline__ void zstore(float* p, float v) {
    __hip_atomic_store(p, v, __ATOMIC_RELAXED, __HIP_MEMORY_SCOPE_AGENT);
}
__device__ __forceinline__ uint32_t pack_pkrtz(float a, float b) {
    pk16_t h = __builtin_amdgcn_cvt_pkrtz(a, b);
    return __builtin_bit_cast(uint32_t, h);
}
__device__ __forceinline__ float fdot2u(uint32_t a, uint32_t b, float acc) {
    half2_t ha = __builtin_bit_cast(half2_t, a);
    half2_t hb = __builtin_bit_cast(half2_t, b);
    return __builtin_amdgcn_fdot2(ha, hb, acc, false);
}

// ---------------- GEMM v3: logits = enc @ W^T + bias, f16 dot2 inner ----------------
__global__ __launch_bounds__(256) void gemm_logits3(
    const float* __restrict__ A, const float* __restrict__ W,
    const float* __restrict__ bias, float* __restrict__ C)
{
    const int K = HID, N = VOC;
    __shared__ uint32_t As2[8][132];   // [k-pair][row]
    __shared__ uint32_t Ws2[8][132];   // [k-pair][col]
    int tid = threadIdx.x;
    int row0 = blockIdx.y << 7;
    int col0 = blockIdx.x << 7;
    int tx = tid & 15, ty = tid >> 4;
    int lr = tid >> 2;
    int lk = (tid & 3) << 2;
    int kp0 = lk >> 1;
    float acc[8][8] = {};
    float bj[8];
    #pragma unroll
    for (int j = 0; j < 8; ++j) bj[j] = bias[col0 + tx * 8 + j];

    for (int k0 = 0; k0 < K; k0 += 16) {
        float4 av0 = *(const float4*)(A + (size_t)(row0 + lr) * K + k0 + lk);
        float4 av1 = *(const float4*)(A + (size_t)(row0 + lr + 64) * K + k0 + lk);
        float4 wv0 = *(const float4*)(W + (size_t)(col0 + lr) * K + k0 + lk);
        float4 wv1 = *(const float4*)(W + (size_t)(col0 + lr + 64) * K + k0 + lk);
        __syncthreads();
        As2[kp0][lr]      = pack_pkrtz(av0.x, av0.y);
        As2[kp0+1][lr]    = pack_pkrtz(av0.z, av0.w);
        As2[kp0][lr+64]   = pack_pkrtz(av1.x, av1.y);
        As2[kp0+1][lr+64] = pack_pkrtz(av1.z, av1.w);
        Ws2[kp0][lr]      = pack_pkrtz(wv0.x, wv0.y);
        Ws2[kp0+1][lr]    = pack_pkrtz(wv0.z, wv0.w);
        Ws2[kp0][lr+64]   = pack_pkrtz(wv1.x, wv1.y);
        Ws2[kp0+1][lr+64] = pack_pkrtz(wv1.z, wv1.w);
        __syncthreads();
        #pragma unroll
        for (int kp = 0; kp < 8; ++kp) {
            uint4 a0 = *(const uint4*)&As2[kp][ty * 8];
            uint4 a1 = *(const uint4*)&As2[kp][ty * 8 + 4];
            uint4 w0 = *(const uint4*)&Ws2[kp][tx * 8];
            uint4 w1 = *(const uint4*)&Ws2[kp][tx * 8 + 4];
            uint32_t ar[8] = {a0.x, a0.y, a0.z, a0.w, a1.x, a1.y, a1.z, a1.w};
            uint32_t wr[8] = {w0.x, w0.y, w0.z, w0.w, w1.x, w1.y, w1.z, w1.w};
            #pragma unroll
            for (int i = 0; i < 8; ++i)
                #pragma unroll
                for (int j = 0; j < 8; ++j)
                    acc[i][j] = fdot2u(ar[i], wr[j], acc[i][j]);
        }
    }
    #pragma unroll
    for (int i = 0; i < 8; ++i) {
        size_t r = row0 + ty * 8 + i;
        float4 o0, o1;
        o0.x = acc[i][0] + bj[0]; o0.y = acc[i][1] + bj[1];
        o0.z = acc[i][2] + bj[2]; o0.w = acc[i][3] + bj[3];
        o1.x = acc[i][4] + bj[4]; o1.y = acc[i][5] + bj[5];
        o1.z = acc[i][6] + bj[6]; o1.w = acc[i][7] + bj[7];
        *(float4*)(C + r * N + col0 + tx * 8)     = o0;
        *(float4*)(C + r * N + col0 + tx * 8 + 4) = o1;
    }
}

// ---------------- Epk[v2][c] = half2(exp(trans[2v2][c]), exp(trans[2v2+1][c])) ----------------
__global__ __launch_bounds__(256) void exp_pack(
    const float* __restrict__ trans, uint32_t* __restrict__ Epk)
{
    int idx = blockIdx.x * 256 + threadIdx.x;
    int v2 = idx >> 10, c = idx & 1023;
    float e0 = __expf(trans[(size_t)(2 * v2) * VOC + c]);
    float e1 = __expf(trans[(size_t)(2 * v2 + 1) * VOC + c]);
    Epk[idx] = pack_pkrtz(e0, e1);
}

// ---------------- persistent CRF scan v7: producer-consumer flags, no barrier ----------------
// grid (16 bg, 16 cc), 512 thr = 8 waves. Wave w stages/computes v2 in [64w,64w+64),
// whose Z columns [128w,128w+128) are produced by blocks {2w,2w+1} -> each wave
// waits on ONE 8-byte flag pair (acquire), not a 16-block barrier. Wave-local max
// (rescaled in finalize by exp(m_w - M)) kills the pre-compute syncthreads.
// 3-buffer Z rotation makes the 2-producer wait race-free: flag(t) transitively
// implies every block finished reading slot t-2.
__global__ __launch_bounds__(512) void crf_scan(
    const float* __restrict__ logits, float* __restrict__ Z0, float* __restrict__ Z1,
    float* __restrict__ Z2, float* __restrict__ Zfin,
    const uint32_t* __restrict__ Epk, const int* __restrict__ lengths,
    unsigned int* __restrict__ flags)
{
    __shared__ float Sred[8][64][3];   // [wave][col][batch], +1 pad
    __shared__ float Mred[8][2];       // wave-local chunk maxes
    int tid  = threadIdx.x;
    int w    = tid >> 6;
    int lane = tid & 63;
    int bg   = blockIdx.x;
    int cc   = blockIdx.y;
    int b0   = bg * 2;

    float* Zbuf[3] = {Z0, Z1, Z2};

    int len2[2];
    len2[0] = lengths[b0];
    len2[1] = lengths[b0 + 1];
    int lmax = max(len2[0], len2[1]);

    int v2s = (w << 6) + lane;             // staged v2; producers = blocks {2w, 2w+1}
    int c   = (cc << 6) + lane;            // own column
    const uint32_t* Ec = Epk + c + ((size_t)(w << 6) << 10);

    const float* src = logits;             // Z0 = logits[t=0] (rows 0..31)
    for (int t = 1; t < TLEN; ++t) {
        if (t >= lmax) break;              // bg-uniform exit; park below
        float* dst = Zbuf[t % 3];

        // (W) wait for this wave's 2 producers of Z(t-1) (skip t==1: src=logits)
        if (t > 1) {
            const unsigned long long* f2 = (const unsigned long long*)
                &flags[((t - 1) << 8) + (bg << 4) + (w << 1)];
            while (__hip_atomic_load(f2, __ATOMIC_ACQUIRE, __HIP_MEMORY_SCOPE_AGENT)
                   != 0x0000000100000001ull) {}
        }

        // (A) staging: 2 cols of both batches, wave-local max only
        float2 z0 = zload2(&src[(size_t)b0 * VOC + 2 * v2s]);
        float2 z1 = zload2(&src[(size_t)(b0 + 1) * VOC + 2 * v2s]);
        float m0 = fmaxf(z0.x, z0.y);
        float m1 = fmaxf(z1.x, z1.y);
        #pragma unroll
        for (int off = 32; off; off >>= 1) {
            m0 = fmaxf(m0, __shfl_xor(m0, off));
            m1 = fmaxf(m1, __shfl_xor(m1, off));
        }
        uint32_t pp0 = pack_pkrtz(__expf(z0.x - m0), __expf(z0.y - m0));
        uint32_t pp1 = pack_pkrtz(__expf(z1.x - m1), __expf(z1.y - m1));
        if (lane == 0) { Mred[w][0] = m0; Mred[w][1] = m1; }

        // prefetch finalize operand (own slice / logits row t)
        float fin = 0.f;
        if (tid < 128) {
            int b = b0 + w;
            if (t < len2[w]) fin = logits[((size_t)t * NB + b) * VOC + c];
            else             fin = zload(&src[(size_t)b * VOC + c]);
        }

        // (C) compute: 64 v2; p lane->SGPR via readlane; split accumulators
        float a0a = 0.f, a0b = 0.f, a1a = 0.f, a1b = 0.f;
        #pragma unroll
        for (int j = 0; j < 64; j += 2) {
            uint32_t e0 = Ec[(size_t)j << 10];
            uint32_t e1 = Ec[(size_t)(j + 1) << 10];
            uint32_t s00 = (uint32_t)__builtin_amdgcn_readlane((int)pp0, j);
            uint32_t s10 = (uint32_t)__builtin_amdgcn_readlane((int)pp1, j);
            uint32_t s01 = (uint32_t)__builtin_amdgcn_readlane((int)pp0, j + 1);
            uint32_t s11 = (uint32_t)__builtin_amdgcn_readlane((int)pp1, j + 1);
            a0a = fdot2u(e0, s00, a0a);
            a1a = fdot2u(e0, s10, a1a);
            a0b = fdot2u(e1, s01, a0b);
            a1b = fdot2u(e1, s11, a1b);
        }
        Sred[w][lane][0] = a0a + a0b;
        Sred[w][lane][1] = a1a + a1b;
        __syncthreads();                   // single mid-step sync

        // (E) finalize: 128 threads, 2 batches x 64 cols; rescale wave partials
        if (tid < 128) {
            float M = Mred[0][w];
            #pragma unroll
            for (int ww = 1; ww < 8; ++ww) M = fmaxf(M, Mred[ww][w]);
            float S = 0.f;
            #pragma unroll
            for (int ww = 0; ww < 8; ++ww)
                S += __expf(Mred[ww][w] - M) * Sred[ww][lane][w];
            int b = b0 + w;
            float outv;
            if (t < len2[w]) outv = fin + M + __logf(S);
            else             outv = fin;
            zstore(&dst[(size_t)b * VOC + c], outv);
        }

        // (S) publish: drain all waves' stores, then release-store this block's flag
        __syncthreads();
        if (tid == 0)
            __hip_atomic_store(&flags[(t << 8) + (bg << 4) + cc], 1u,
                               __ATOMIC_RELEASE, __HIP_MEMORY_SCOPE_AGENT);
        src = dst;
    }

    // park final Z (own slice) into Zfin with plain stores (kernel-boundary coherent)
    if (tid < 128) {
        int b = b0 + w;
        Zfin[(size_t)b * VOC + c] = zload(&src[(size_t)b * VOC + c]);
    }
}

// ---------------- epilogue ----------------
__global__ __launch_bounds__(256) void crf_finish(
    const float* __restrict__ Zfin, const float* __restrict__ logits,
    const float* __restrict__ trans, const int* __restrict__ targets,
    const int* __restrict__ lengths, float* __restrict__ out)
{
    __shared__ float part[NB];
    int tid = threadIdx.x;
    int b = tid >> 3, j = tid & 7;
    const float* zr = Zfin + (size_t)b * VOC;
    float m = -1e30f;
    for (int v = j; v < VOC; v += 8) m = fmaxf(m, zr[v]);
    #pragma unroll
    for (int off = 1; off < 8; off <<= 1) m = fmaxf(m, __shfl_xor(m, off));
    float s = 0.f;
    for (int v = j; v < VOC; v += 8) s += __expf(zr[v] - m);
    #pragma unroll
    for (int off = 1; off < 8; off <<= 1) s += __shfl_xor(s, off);
    float logZ = m + __logf(s);
    int len = lengths[b];
    float acc = 0.f;
    for (int t = j; t < TLEN; t += 8) {
        if (t < len) {
            int tg = targets[t * NB + b];
            acc += logits[((size_t)t * NB + b) * VOC + tg];
            if (t >= 1) acc += trans[(size_t)targets[(t - 1) * NB + b] * VOC + tg];
        }
    }
    #pragma unroll
    for (int off = 1; off < 8; off <<= 1) acc += __shfl_xor(acc, off);
    if (j == 0) part[b] = logZ - acc;
    __syncthreads();
    if (tid == 0) {
        float sum = 0.f;
        #pragma unroll
        for (int i = 0; i < NB; ++i) sum += part[i];
        out[0] = sum / (float)NB;
    }
}

extern "C" void kernel_launch(void* const* d_in, const int* in_sizes, int n_in,
                              void* d_out, int out_size, void* d_ws, size_t ws_size,
                              hipStream_t stream)
{
    const float* enc   = (const float*)d_in[0];
    const float* W     = (const float*)d_in[1];
    const float* bias  = (const float*)d_in[2];
    const float* trans = (const float*)d_in[3];
    const int* targets = (const int*)d_in[4];
    const int* lengths = (const int*)d_in[5];
    float* out = (float*)d_out;

    // ws: logits 33.5MB | Epk 2MB | Z0/Z1/Z2/Zfin 128KB each | flags 256KB
    float* ws     = (float*)d_ws;
    float* logits = ws;
    uint32_t* Epk = (uint32_t*)(logits + (size_t)TLEN * NB * VOC);
    float* Z0     = (float*)(Epk + (size_t)(VOC / 2) * VOC);
    float* Z1     = Z0 + (size_t)NB * VOC;
    float* Z2     = Z1 + (size_t)NB * VOC;
    float* Zfin   = Z2 + (size_t)NB * VOC;
    unsigned int* flags = (unsigned int*)(Zfin + (size_t)NB * VOC);

    (void)hipMemsetAsync(flags, 0, TLEN * 256 * sizeof(unsigned int), stream);
    gemm_logits3<<<dim3(VOC / 128, TLEN * NB / 128), 256, 0, stream>>>(enc, W, bias, logits);
    exp_pack<<<dim3((VOC / 2) * VOC / 256), 256, 0, stream>>>(trans, Epk);
    crf_scan<<<dim3(16, 16), 512, 0, stream>>>(logits, Z0, Z1, Z2, Zfin, Epk, lengths, flags);
    crf_finish<<<1, 256, 0, stream>>>(Zfin, logits, trans, targets, lengths, out);
}

// Round 11
// 863.720 us; speedup vs baseline: 7.2648x; 7.2648x over previous
//
#include <hip/hip_runtime.h>
#include <math.h>
#include <stdint.h>

#define TLEN 256
#define NB   32
#define HID  512
#define VOC  1024

typedef __attribute__((ext_vector_type(2))) _Float16 half2_t;
typedef __attribute__((ext_vector_type(2))) __fp16  pk16_t;

// ---- device-coherent (agent-scope) Z accessors ----
__device__ __forceinline__ float zload(const float* p) {
    return __hip_atomic_load(p, __ATOMIC_RELAXED, __HIP_MEMORY_SCOPE_AGENT);
}
__device__ __forceinline__ float2 zload2(const float* p) {
    unsigned long long u = __hip_atomic_load((const unsigned long long*)p,
                                             __ATOMIC_RELAXED, __HIP_MEMORY_SCOPE_AGENT);
    union { unsigned long long u; float2 f; } c; c.u = u; return c.f;
}
__device__ __forceinline__ void zstore(float* p, float v) {
    __hip_atomic_store(p, v, __ATOMIC_RELAXED, __HIP_MEMORY_SCOPE_AGENT);
}
__device__ __forceinline__ uint32_t pack_pkrtz(float a, float b) {
    pk16_t h = __builtin_amdgcn_cvt_pkrtz(a, b);
    return __builtin_bit_cast(uint32_t, h);
}
__device__ __forceinline__ float fdot2u(uint32_t a, uint32_t b, float acc) {
    half2_t ha = __builtin_bit_cast(half2_t, a);
    half2_t hb = __builtin_bit_cast(half2_t, b);
    return __builtin_amdgcn_fdot2(ha, hb, acc, false);
}
__device__ __forceinline__ int udot4(uint32_t a, uint32_t b, int acc) {
#if __has_builtin(__builtin_amdgcn_udot4)
    return __builtin_amdgcn_udot4(a, b, acc, false);
#else
    return acc + (int)((a & 255u) * (b & 255u))
               + (int)(((a >> 8) & 255u) * ((b >> 8) & 255u))
               + (int)(((a >> 16) & 255u) * ((b >> 16) & 255u))
               + (int)((a >> 24) * (b >> 24));
#endif
}

// ---------------- GEMM v3: logits = enc @ W^T + bias, f16 dot2 inner ----------------
__global__ __launch_bounds__(256) void gemm_logits3(
    const float* __restrict__ A, const float* __restrict__ W,
    const float* __restrict__ bias, float* __restrict__ C)
{
    const int K = HID, N = VOC;
    __shared__ uint32_t As2[8][132];   // [k-pair][row]
    __shared__ uint32_t Ws2[8][132];   // [k-pair][col]
    int tid = threadIdx.x;
    int row0 = blockIdx.y << 7;
    int col0 = blockIdx.x << 7;
    int tx = tid & 15, ty = tid >> 4;
    int lr = tid >> 2;
    int lk = (tid & 3) << 2;
    int kp0 = lk >> 1;
    float acc[8][8] = {};
    float bj[8];
    #pragma unroll
    for (int j = 0; j < 8; ++j) bj[j] = bias[col0 + tx * 8 + j];

    for (int k0 = 0; k0 < K; k0 += 16) {
        float4 av0 = *(const float4*)(A + (size_t)(row0 + lr) * K + k0 + lk);
        float4 av1 = *(const float4*)(A + (size_t)(row0 + lr + 64) * K + k0 + lk);
        float4 wv0 = *(const float4*)(W + (size_t)(col0 + lr) * K + k0 + lk);
        float4 wv1 = *(const float4*)(W + (size_t)(col0 + lr + 64) * K + k0 + lk);
        __syncthreads();
        As2[kp0][lr]      = pack_pkrtz(av0.x, av0.y);
        As2[kp0+1][lr]    = pack_pkrtz(av0.z, av0.w);
        As2[kp0][lr+64]   = pack_pkrtz(av1.x, av1.y);
        As2[kp0+1][lr+64] = pack_pkrtz(av1.z, av1.w);
        Ws2[kp0][lr]      = pack_pkrtz(wv0.x, wv0.y);
        Ws2[kp0+1][lr]    = pack_pkrtz(wv0.z, wv0.w);
        Ws2[kp0][lr+64]   = pack_pkrtz(wv1.x, wv1.y);
        Ws2[kp0+1][lr+64] = pack_pkrtz(wv1.z, wv1.w);
        __syncthreads();
        #pragma unroll
        for (int kp = 0; kp < 8; ++kp) {
            uint4 a0 = *(const uint4*)&As2[kp][ty * 8];
            uint4 a1 = *(const uint4*)&As2[kp][ty * 8 + 4];
            uint4 w0 = *(const uint4*)&Ws2[kp][tx * 8];
            uint4 w1 = *(const uint4*)&Ws2[kp][tx * 8 + 4];
            uint32_t ar[8] = {a0.x, a0.y, a0.z, a0.w, a1.x, a1.y, a1.z, a1.w};
            uint32_t wr[8] = {w0.x, w0.y, w0.z, w0.w, w1.x, w1.y, w1.z, w1.w};
            #pragma unroll
            for (int i = 0; i < 8; ++i)
                #pragma unroll
                for (int j = 0; j < 8; ++j)
                    acc[i][j] = fdot2u(ar[i], wr[j], acc[i][j]);
        }
    }
    #pragma unroll
    for (int i = 0; i < 8; ++i) {
        size_t r = row0 + ty * 8 + i;
        float4 o0, o1;
        o0.x = acc[i][0] + bj[0]; o0.y = acc[i][1] + bj[1];
        o0.z = acc[i][2] + bj[2]; o0.w = acc[i][3] + bj[3];
        o1.x = acc[i][4] + bj[4]; o1.y = acc[i][5] + bj[5];
        o1.z = acc[i][6] + bj[6]; o1.w = acc[i][7] + bj[7];
        *(float4*)(C + r * N + col0 + tx * 8)     = o0;
        *(float4*)(C + r * N + col0 + tx * 8 + 4) = o1;
    }
}

// ---------------- E4[v4][c] = u8x4( round(exp(trans[4v4+k][c]) * 196) ) ----------------
__global__ __launch_bounds__(256) void e4_pack(
    const float* __restrict__ trans, uint32_t* __restrict__ E4)
{
    int idx = blockIdx.x * 256 + threadIdx.x;   // over 256*1024
    int v4 = idx >> 10, c = idx & 1023;
    uint32_t r = 0;
    #pragma unroll
    for (int k = 0; k < 4; ++k) {
        float e = __expf(trans[(size_t)(4 * v4 + k) * VOC + c]) * 196.f;
        uint32_t q = (uint32_t)__float2uint_rn(fminf(e, 255.f));
        r |= q << (8 * k);
    }
    E4[idx] = r;
}

// ---------------- persistent CRF scan v8: u8 dot4 ----------------
// grid (16 bg, 16 cc), 512 thr = 8 waves; block = batches {2bg,2bg+1} x 64 cols.
// Wave w covers v in [128w, 128w+128): half-lanes 0..31 stage 4 v each of batch0
// (quantized p*255 packed u8x4), lanes 32..63 batch1. Compute: readlane -> SGPR,
// v_dot4_u32_u8 against E4 (u8, x196). Wave-local max, rescaled in finalize:
// S = sum_w exp(m_w - M) * S_int_w / (255*196).
__global__ __launch_bounds__(512) void crf_scan(
    const float* __restrict__ logits, float* __restrict__ Za, float* __restrict__ Zb,
    const uint32_t* __restrict__ E4, const int* __restrict__ lengths,
    unsigned int* __restrict__ cnt)
{
    __shared__ float Sred[8][64][3];   // [wave][col][batch], +1 pad
    __shared__ float Mred[8][2];       // wave-local chunk maxes per batch
    int tid  = threadIdx.x;
    int w    = tid >> 6;
    int lane = tid & 63;
    int h    = lane >> 5;              // staged batch half
    int li   = lane & 31;              // v4 slot within wave
    int bg   = blockIdx.x;
    int cc   = blockIdx.y;
    int b0   = bg * 2;

    int len2[2];
    len2[0] = lengths[b0];
    len2[1] = lengths[b0 + 1];
    int lmax = max(len2[0], len2[1]);

    int c = (cc << 6) + lane;                            // own column
    const uint32_t* Ec = E4 + c + ((size_t)(w << 5) << 10);  // rows 32w.., stride 1024

    const float* src = logits;         // Z0 = logits[t=0] (rows 0..31)
    for (int t = 1; t < TLEN; ++t) {
        float* dst = (t & 1) ? Za : Zb;
        if (t >= lmax) {               // uniform across this bg's 16 blocks
            if (src != Za && tid < 128) {
                int b = b0 + w;
                Za[(size_t)b * VOC + c] = zload(&src[(size_t)b * VOC + c]);
            }
            return;
        }
        // (A) staging: thread loads 4 v of its half's batch; wave-half max
        const float* zp = src + (size_t)(b0 + h) * VOC + (w << 7) + (li << 2);
        float2 za = zload2(zp);
        float2 zb = zload2(zp + 2);
        // prefetch finalize operand early (overlaps with reduce/quant)
        float fin = 0.f;
        if (tid < 128) {
            int b = b0 + w;
            if (t < len2[w]) fin = logits[((size_t)t * NB + b) * VOC + c];
            else             fin = zload(&src[(size_t)b * VOC + c]);
        }
        float m = fmaxf(fmaxf(za.x, za.y), fmaxf(zb.x, zb.y));
        #pragma unroll
        for (int off = 16; off; off >>= 1) m = fmaxf(m, __shfl_xor(m, off));
        if (li == 0) Mred[w][h] = m;
        uint32_t q0 = (uint32_t)__float2uint_rn(__expf(za.x - m) * 255.f);
        uint32_t q1 = (uint32_t)__float2uint_rn(__expf(za.y - m) * 255.f);
        uint32_t q2 = (uint32_t)__float2uint_rn(__expf(zb.x - m) * 255.f);
        uint32_t q3 = (uint32_t)__float2uint_rn(__expf(zb.y - m) * 255.f);
        uint32_t pp = q0 | (q1 << 8) | (q2 << 16) | (q3 << 24);

        // (C) compute: 32 v4-rows; p lane->SGPR via readlane; split accumulators
        int a0a = 0, a0b = 0, a1a = 0, a1b = 0;
        #pragma unroll
        for (int j = 0; j < 32; j += 2) {
            uint32_t e0 = Ec[(size_t)j << 10];
            uint32_t e1 = Ec[(size_t)(j + 1) << 10];
            uint32_t s00 = (uint32_t)__builtin_amdgcn_readlane((int)pp, j);
            uint32_t s10 = (uint32_t)__builtin_amdgcn_readlane((int)pp, j + 32);
            uint32_t s01 = (uint32_t)__builtin_amdgcn_readlane((int)pp, j + 1);
            uint32_t s11 = (uint32_t)__builtin_amdgcn_readlane((int)pp, j + 33);
            a0a = udot4(e0, s00, a0a);
            a1a = udot4(e0, s10, a1a);
            a0b = udot4(e1, s01, a0b);
            a1b = udot4(e1, s11, a1b);
        }
        Sred[w][lane][0] = (float)(a0a + a0b);
        Sred[w][lane][1] = (float)(a1a + a1b);
        __syncthreads();

        // (E) finalize: 128 threads, 2 batches x 64 cols; rescale wave partials
        if (tid < 128) {
            float M = Mred[0][w];
            #pragma unroll
            for (int ww = 1; ww < 8; ++ww) M = fmaxf(M, Mred[ww][w]);
            float S = 0.f;
            #pragma unroll
            for (int ww = 0; ww < 8; ++ww)
                S += __expf(Mred[ww][w] - M) * Sred[ww][lane][w];
            int b = b0 + w;
            float outv;
            if (t < len2[w]) outv = fin + M + __logf(S * (1.0f / (255.f * 196.f)));
            else             outv = fin;
            zstore(&dst[(size_t)b * VOC + c], outv);
        }

        // (F) inter-block barrier among this bg's 16 blocks
        __syncthreads();               // drains vmcnt(0): Z stores visible
        if (tid == 0) {
            unsigned int* c16 = &cnt[t * 16 + bg];
            __hip_atomic_fetch_add(c16, 1u, __ATOMIC_RELAXED, __HIP_MEMORY_SCOPE_AGENT);
            while (__hip_atomic_load(c16, __ATOMIC_RELAXED, __HIP_MEMORY_SCOPE_AGENT) < 16u)
                __builtin_amdgcn_s_sleep(1);
        }
        __syncthreads();
        src = dst;
    }
}

// ---------------- epilogue ----------------
__global__ __launch_bounds__(256) void crf_finish(
    const float* __restrict__ Zfin, const float* __restrict__ logits,
    const float* __restrict__ trans, const int* __restrict__ targets,
    const int* __restrict__ lengths, float* __restrict__ out)
{
    __shared__ float part[NB];
    int tid = threadIdx.x;
    int b = tid >> 3, j = tid & 7;
    const float* zr = Zfin + (size_t)b * VOC;
    float m = -1e30f;
    for (int v = j; v < VOC; v += 8) m = fmaxf(m, zr[v]);
    #pragma unroll
    for (int off = 1; off < 8; off <<= 1) m = fmaxf(m, __shfl_xor(m, off));
    float s = 0.f;
    for (int v = j; v < VOC; v += 8) s += __expf(zr[v] - m);
    #pragma unroll
    for (int off = 1; off < 8; off <<= 1) s += __shfl_xor(s, off);
    float logZ = m + __logf(s);
    int len = lengths[b];
    float acc = 0.f;
    for (int t = j; t < TLEN; t += 8) {
        if (t < len) {
            int tg = targets[t * NB + b];
            acc += logits[((size_t)t * NB + b) * VOC + tg];
            if (t >= 1) acc += trans[(size_t)targets[(t - 1) * NB + b] * VOC + tg];
        }
    }
    #pragma unroll
    for (int off = 1; off < 8; off <<= 1) acc += __shfl_xor(acc, off);
    if (j == 0) part[b] = logZ - acc;
    __syncthreads();
    if (tid == 0) {
        float sum = 0.f;
        #pragma unroll
        for (int i = 0; i < NB; ++i) sum += part[i];
        out[0] = sum / (float)NB;
    }
}

extern "C" void kernel_launch(void* const* d_in, const int* in_sizes, int n_in,
                              void* d_out, int out_size, void* d_ws, size_t ws_size,
                              hipStream_t stream)
{
    const float* enc   = (const float*)d_in[0];
    const float* W     = (const float*)d_in[1];
    const float* bias  = (const float*)d_in[2];
    const float* trans = (const float*)d_in[3];
    const int* targets = (const int*)d_in[4];
    const int* lengths = (const int*)d_in[5];
    float* out = (float*)d_out;

    // ws: logits 33.5MB | E4 1MB | Za 128KB | Zb 128KB | cnt 16KB
    float* ws     = (float*)d_ws;
    float* logits = ws;
    uint32_t* E4  = (uint32_t*)(logits + (size_t)TLEN * NB * VOC);
    float* Za     = (float*)(E4 + (size_t)(VOC / 4) * VOC);
    float* Zb     = Za + (size_t)NB * VOC;
    unsigned int* cnt = (unsigned int*)(Zb + (size_t)NB * VOC);

    (void)hipMemsetAsync(cnt, 0, TLEN * 16 * sizeof(unsigned int), stream);
    gemm_logits3<<<dim3(VOC / 128, TLEN * NB / 128), 256, 0, stream>>>(enc, W, bias, logits);
    e4_pack<<<dim3((VOC / 4) * VOC / 256), 256, 0, stream>>>(trans, E4);
    crf_scan<<<dim3(16, 16), 512, 0, stream>>>(logits, Za, Zb, E4, lengths, cnt);
    crf_finish<<<1, 256, 0, stream>>>(Za, logits, trans, targets, lengths, out);
}

// Round 12
// 741.481 us; speedup vs baseline: 8.4625x; 1.1649x over previous
//
#include <hip/hip_runtime.h>
#include <math.h>
#include <stdint.h>

#define TLEN 256
#define NB   32
#define HID  512
#define VOC  1024

typedef __attribute__((ext_vector_type(2))) _Float16 half2_t;
typedef __attribute__((ext_vector_type(2))) __fp16  pk16_t;
typedef __attribute__((ext_vector_type(8))) _Float16 v8h;
typedef __attribute__((ext_vector_type(4))) float    v4f;

// ---- device-coherent (agent-scope) Z accessors ----
__device__ __forceinline__ float zload(const float* p) {
    return __hip_atomic_load(p, __ATOMIC_RELAXED, __HIP_MEMORY_SCOPE_AGENT);
}
__device__ __forceinline__ float2 zload2(const float* p) {
    unsigned long long u = __hip_atomic_load((const unsigned long long*)p,
                                             __ATOMIC_RELAXED, __HIP_MEMORY_SCOPE_AGENT);
    union { unsigned long long u; float2 f; } c; c.u = u; return c.f;
}
__device__ __forceinline__ void zstore(float* p, float v) {
    __hip_atomic_store(p, v, __ATOMIC_RELAXED, __HIP_MEMORY_SCOPE_AGENT);
}
__device__ __forceinline__ uint32_t pack_pkrtz(float a, float b) {
    pk16_t h = __builtin_amdgcn_cvt_pkrtz(a, b);
    return __builtin_bit_cast(uint32_t, h);
}
__device__ __forceinline__ int udot4(uint32_t a, uint32_t b, int acc) {
#if __has_builtin(__builtin_amdgcn_udot4)
    return __builtin_amdgcn_udot4(a, b, acc, false);
#else
    return acc + (int)((a & 255u) * (b & 255u))
               + (int)(((a >> 8) & 255u) * ((b >> 8) & 255u))
               + (int)(((a >> 16) & 255u) * ((b >> 16) & 255u))
               + (int)((a >> 24) * (b >> 24));
#endif
}

// ---------------- GEMM v4: MFMA f16 16x16x32, 128x128 tile ----------------
// A (M=8192,K=512) f32 row-major; W (N=1024,K=512) f32 row-major; C = A@W^T + bias.
// Verified layouts (cdna4 guide): A/B operand [m|n]=lane&15, k=(lane>>4)*8+j;
// C/D c=lane&15, r=(lane>>4)*4+reg. LDS stride 40 f16 (80B) -> 2-way conflicts (free).
__global__ __launch_bounds__(256) void gemm_mfma(
    const float* __restrict__ A, const float* __restrict__ W,
    const float* __restrict__ bias, float* __restrict__ C)
{
    const int K = HID, N = VOC;
    __shared__ _Float16 As[128][40];
    __shared__ _Float16 Ws[128][40];
    int tid  = threadIdx.x;
    int wv   = tid >> 6;
    int lane = tid & 63;
    int wy = wv >> 1, wx = wv & 1;
    int quad = lane >> 4, l16 = lane & 15;
    int row0 = blockIdx.y << 7;
    int col0 = blockIdx.x << 7;

    v4f acc[4][4] = {};

    int sr = tid >> 1;             // staging row 0..127
    int sk = (tid & 1) << 4;       // k-half 0 / 16

    for (int k0 = 0; k0 < K; k0 += 32) {
        const float* ap = A + (size_t)(row0 + sr) * K + k0 + sk;
        const float* wp = W + (size_t)(col0 + sr) * K + k0 + sk;
        float4 a0 = *(const float4*)(ap);
        float4 a1 = *(const float4*)(ap + 4);
        float4 a2 = *(const float4*)(ap + 8);
        float4 a3 = *(const float4*)(ap + 12);
        float4 w0 = *(const float4*)(wp);
        float4 w1 = *(const float4*)(wp + 4);
        float4 w2 = *(const float4*)(wp + 8);
        float4 w3 = *(const float4*)(wp + 12);
        __syncthreads();           // protect previous iteration's reads
        uint32_t* ad = (uint32_t*)&As[sr][sk];
        ad[0] = pack_pkrtz(a0.x, a0.y); ad[1] = pack_pkrtz(a0.z, a0.w);
        ad[2] = pack_pkrtz(a1.x, a1.y); ad[3] = pack_pkrtz(a1.z, a1.w);
        ad[4] = pack_pkrtz(a2.x, a2.y); ad[5] = pack_pkrtz(a2.z, a2.w);
        ad[6] = pack_pkrtz(a3.x, a3.y); ad[7] = pack_pkrtz(a3.z, a3.w);
        uint32_t* wd = (uint32_t*)&Ws[sr][sk];
        wd[0] = pack_pkrtz(w0.x, w0.y); wd[1] = pack_pkrtz(w0.z, w0.w);
        wd[2] = pack_pkrtz(w1.x, w1.y); wd[3] = pack_pkrtz(w1.z, w1.w);
        wd[4] = pack_pkrtz(w2.x, w2.y); wd[5] = pack_pkrtz(w2.z, w2.w);
        wd[6] = pack_pkrtz(w3.x, w3.y); wd[7] = pack_pkrtz(w3.z, w3.w);
        __syncthreads();
        v8h af[4], bf[4];
        #pragma unroll
        for (int i = 0; i < 4; ++i)
            af[i] = *(const v8h*)&As[wy * 64 + i * 16 + l16][quad * 8];
        #pragma unroll
        for (int j = 0; j < 4; ++j)
            bf[j] = *(const v8h*)&Ws[wx * 64 + j * 16 + l16][quad * 8];
        #pragma unroll
        for (int i = 0; i < 4; ++i)
            #pragma unroll
            for (int j = 0; j < 4; ++j)
                acc[i][j] = __builtin_amdgcn_mfma_f32_16x16x32_f16(af[i], bf[j], acc[i][j], 0, 0, 0);
    }
    #pragma unroll
    for (int i = 0; i < 4; ++i) {
        #pragma unroll
        for (int j = 0; j < 4; ++j) {
            int ccol = col0 + wx * 64 + j * 16 + l16;
            float bb = bias[ccol];
            #pragma unroll
            for (int r = 0; r < 4; ++r) {
                int rrow = row0 + wy * 64 + i * 16 + quad * 4 + r;
                C[(size_t)rrow * N + ccol] = acc[i][j][r] + bb;
            }
        }
    }
}

// ---------------- E4[v4][c] = u8x4( round(exp(trans[4v4+k][c]) * 196) ) ----------------
__global__ __launch_bounds__(256) void e4_pack(
    const float* __restrict__ trans, uint32_t* __restrict__ E4)
{
    int idx = blockIdx.x * 256 + threadIdx.x;   // over 256*1024
    int v4 = idx >> 10, c = idx & 1023;
    uint32_t r = 0;
    #pragma unroll
    for (int k = 0; k < 4; ++k) {
        float e = __expf(trans[(size_t)(4 * v4 + k) * VOC + c]) * 196.f;
        uint32_t q = (uint32_t)__float2uint_rn(fminf(e, 255.f));
        r |= q << (8 * k);
    }
    E4[idx] = r;
}

// ---------------- persistent CRF scan v9: u8 dot4, E resident in VGPRs ----------------
// grid (16 bg, 16 cc), 512 thr = 8 waves. E is constant across steps: each lane
// preloads its 32 u8x4 E values ONCE -> hot loop is pure VALU (readlane + dot4),
// VMEM serves only the Z exchange.
__global__ __launch_bounds__(512) void crf_scan(
    const float* __restrict__ logits, float* __restrict__ Za, float* __restrict__ Zb,
    const uint32_t* __restrict__ E4, const int* __restrict__ lengths,
    unsigned int* __restrict__ cnt)
{
    __shared__ float Sred[8][64][3];   // [wave][col][batch], +1 pad
    __shared__ float Mred[8][2];       // wave-local chunk maxes per batch
    int tid  = threadIdx.x;
    int w    = tid >> 6;
    int lane = tid & 63;
    int h    = lane >> 5;              // staged batch half
    int li   = lane & 31;              // v4 slot within wave half
    int bg   = blockIdx.x;
    int cc   = blockIdx.y;
    int b0   = bg * 2;

    int len2[2];
    len2[0] = lengths[b0];
    len2[1] = lengths[b0 + 1];
    int lmax = max(len2[0], len2[1]);

    int c = (cc << 6) + lane;                                // own column
    const uint32_t* Ec = E4 + c + ((size_t)(w << 5) << 10);  // 32 rows, stride 1024

    uint32_t Ereg[32];                 // E slice resident for the whole scan
    #pragma unroll
    for (int j = 0; j < 32; ++j) Ereg[j] = Ec[(size_t)j << 10];

    const float* src = logits;         // Z0 = logits[t=0] (rows 0..31)
    for (int t = 1; t < TLEN; ++t) {
        float* dst = (t & 1) ? Za : Zb;
        if (t >= lmax) {               // uniform across this bg's 16 blocks
            if (src != Za && tid < 128) {
                int b = b0 + w;
                Za[(size_t)b * VOC + c] = zload(&src[(size_t)b * VOC + c]);
            }
            return;
        }
        // (A) staging: thread loads 4 v of its half's batch; half-wave max
        const float* zp = src + (size_t)(b0 + h) * VOC + (w << 7) + (li << 2);
        float2 za = zload2(zp);
        float2 zb = zload2(zp + 2);
        // prefetch finalize operand (overlaps with reduce/quant/compute)
        float fin = 0.f;
        if (tid < 128) {
            int b = b0 + w;
            if (t < len2[w]) fin = logits[((size_t)t * NB + b) * VOC + c];
            else             fin = zload(&src[(size_t)b * VOC + c]);
        }
        float m = fmaxf(fmaxf(za.x, za.y), fmaxf(zb.x, zb.y));
        #pragma unroll
        for (int off = 16; off; off >>= 1) m = fmaxf(m, __shfl_xor(m, off));
        if (li == 0) Mred[w][h] = m;
        uint32_t q0 = (uint32_t)__float2uint_rn(__expf(za.x - m) * 255.f);
        uint32_t q1 = (uint32_t)__float2uint_rn(__expf(za.y - m) * 255.f);
        uint32_t q2 = (uint32_t)__float2uint_rn(__expf(zb.x - m) * 255.f);
        uint32_t q3 = (uint32_t)__float2uint_rn(__expf(zb.y - m) * 255.f);
        uint32_t pp = q0 | (q1 << 8) | (q2 << 16) | (q3 << 24);

        // (C) compute: 32 v4-rows, E from registers; p lane->SGPR via readlane
        int a0a = 0, a0b = 0, a1a = 0, a1b = 0;
        #pragma unroll
        for (int j = 0; j < 32; j += 2) {
            uint32_t s00 = (uint32_t)__builtin_amdgcn_readlane((int)pp, j);
            uint32_t s10 = (uint32_t)__builtin_amdgcn_readlane((int)pp, j + 32);
            uint32_t s01 = (uint32_t)__builtin_amdgcn_readlane((int)pp, j + 1);
            uint32_t s11 = (uint32_t)__builtin_amdgcn_readlane((int)pp, j + 33);
            a0a = udot4(Ereg[j], s00, a0a);
            a1a = udot4(Ereg[j], s10, a1a);
            a0b = udot4(Ereg[j + 1], s01, a0b);
            a1b = udot4(Ereg[j + 1], s11, a1b);
        }
        Sred[w][lane][0] = (float)(a0a + a0b);
        Sred[w][lane][1] = (float)(a1a + a1b);
        __syncthreads();

        // (E) finalize: 128 threads, 2 batches x 64 cols; rescale wave partials
        if (tid < 128) {
            float M = Mred[0][w];
            #pragma unroll
            for (int ww = 1; ww < 8; ++ww) M = fmaxf(M, Mred[ww][w]);
            float S = 0.f;
            #pragma unroll
            for (int ww = 0; ww < 8; ++ww)
                S += __expf(Mred[ww][w] - M) * Sred[ww][lane][w];
            int b = b0 + w;
            float outv;
            if (t < len2[w]) outv = fin + M + __logf(S * (1.0f / (255.f * 196.f)));
            else             outv = fin;
            zstore(&dst[(size_t)b * VOC + c], outv);
        }

        // (F) inter-block barrier among this bg's 16 blocks
        __syncthreads();               // drains vmcnt(0): Z stores visible
        if (tid == 0) {
            unsigned int* c16 = &cnt[t * 16 + bg];
            __hip_atomic_fetch_add(c16, 1u, __ATOMIC_RELAXED, __HIP_MEMORY_SCOPE_AGENT);
            while (__hip_atomic_load(c16, __ATOMIC_RELAXED, __HIP_MEMORY_SCOPE_AGENT) < 16u)
                __builtin_amdgcn_s_sleep(1);
        }
        __syncthreads();
        src = dst;
    }
}

// ---------------- epilogue ----------------
__global__ __launch_bounds__(256) void crf_finish(
    const float* __restrict__ Zfin, const float* __restrict__ logits,
    const float* __restrict__ trans, const int* __restrict__ targets,
    const int* __restrict__ lengths, float* __restrict__ out)
{
    __shared__ float part[NB];
    int tid = threadIdx.x;
    int b = tid >> 3, j = tid & 7;
    const float* zr = Zfin + (size_t)b * VOC;
    float m = -1e30f;
    for (int v = j; v < VOC; v += 8) m = fmaxf(m, zr[v]);
    #pragma unroll
    for (int off = 1; off < 8; off <<= 1) m = fmaxf(m, __shfl_xor(m, off));
    float s = 0.f;
    for (int v = j; v < VOC; v += 8) s += __expf(zr[v] - m);
    #pragma unroll
    for (int off = 1; off < 8; off <<= 1) s += __shfl_xor(s, off);
    float logZ = m + __logf(s);
    int len = lengths[b];
    float acc = 0.f;
    for (int t = j; t < TLEN; t += 8) {
        if (t < len) {
            int tg = targets[t * NB + b];
            acc += logits[((size_t)t * NB + b) * VOC + tg];
            if (t >= 1) acc += trans[(size_t)targets[(t - 1) * NB + b] * VOC + tg];
        }
    }
    #pragma unroll
    for (int off = 1; off < 8; off <<= 1) acc += __shfl_xor(acc, off);
    if (j == 0) part[b] = logZ - acc;
    __syncthreads();
    if (tid == 0) {
        float sum = 0.f;
        #pragma unroll
        for (int i = 0; i < NB; ++i) sum += part[i];
        out[0] = sum / (float)NB;
    }
}

extern "C" void kernel_launch(void* const* d_in, const int* in_sizes, int n_in,
                              void* d_out, int out_size, void* d_ws, size_t ws_size,
                              hipStream_t stream)
{
    const float* enc   = (const float*)d_in[0];
    const float* W     = (const float*)d_in[1];
    const float* bias  = (const float*)d_in[2];
    const float* trans = (const float*)d_in[3];
    const int* targets = (const int*)d_in[4];
    const int* lengths = (const int*)d_in[5];
    float* out = (float*)d_out;

    // ws: logits 33.5MB | E4 1MB | Za 128KB | Zb 128KB | cnt 16KB
    float* ws     = (float*)d_ws;
    float* logits = ws;
    uint32_t* E4  = (uint32_t*)(logits + (size_t)TLEN * NB * VOC);
    float* Za     = (float*)(E4 + (size_t)(VOC / 4) * VOC);
    float* Zb     = Za + (size_t)NB * VOC;
    unsigned int* cnt = (unsigned int*)(Zb + (size_t)NB * VOC);

    (void)hipMemsetAsync(cnt, 0, TLEN * 16 * sizeof(unsigned int), stream);
    gemm_mfma<<<dim3(VOC / 128, TLEN * NB / 128), 256, 0, stream>>>(enc, W, bias, logits);
    e4_pack<<<dim3((VOC / 4) * VOC / 256), 256, 0, stream>>>(trans, E4);
    crf_scan<<<dim3(16, 16), 512, 0, stream>>>(logits, Za, Zb, E4, lengths, cnt);
    crf_finish<<<1, 256, 0, stream>>>(Za, logits, trans, targets, lengths, out);
}

// Round 13
// 665.367 us; speedup vs baseline: 9.4305x; 1.1144x over previous
//
#include <hip/hip_runtime.h>
#include <math.h>
#include <stdint.h>

#define TLEN 256
#define NB   32
#define HID  512
#define VOC  1024

typedef __attribute__((ext_vector_type(2))) _Float16 half2_t;
typedef __attribute__((ext_vector_type(2))) __fp16  pk16_t;
typedef __attribute__((ext_vector_type(8))) _Float16 v8h;
typedef __attribute__((ext_vector_type(4))) float    v4f;

// ---- device-coherent (agent-scope) Z accessors ----
__device__ __forceinline__ float zload(const float* p) {
    return __hip_atomic_load(p, __ATOMIC_RELAXED, __HIP_MEMORY_SCOPE_AGENT);
}
__device__ __forceinline__ float2 zload2(const float* p) {
    unsigned long long u = __hip_atomic_load((const unsigned long long*)p,
                                             __ATOMIC_RELAXED, __HIP_MEMORY_SCOPE_AGENT);
    union { unsigned long long u; float2 f; } c; c.u = u; return c.f;
}
__device__ __forceinline__ void zstore(float* p, float v) {
    __hip_atomic_store(p, v, __ATOMIC_RELAXED, __HIP_MEMORY_SCOPE_AGENT);
}
__device__ __forceinline__ uint32_t pack_pkrtz(float a, float b) {
    pk16_t h = __builtin_amdgcn_cvt_pkrtz(a, b);
    return __builtin_bit_cast(uint32_t, h);
}
__device__ __forceinline__ int udot4(uint32_t a, uint32_t b, int acc) {
#if __has_builtin(__builtin_amdgcn_udot4)
    return __builtin_amdgcn_udot4(a, b, acc, false);
#else
    return acc + (int)((a & 255u) * (b & 255u))
               + (int)(((a >> 8) & 255u) * ((b >> 8) & 255u))
               + (int)(((a >> 16) & 255u) * ((b >> 16) & 255u))
               + (int)((a >> 24) * (b >> 24));
#endif
}

// ---------------- GEMM v5: MFMA f16 16x16x32, 128x128 tile, reg prefetch ----------------
// A (8192,512) f32; W (1024,512) f32; C = A@W^T + bias. K-tile k+1 preloaded into
// registers between LDS-fill sync and MFMA block -> HBM latency hides under MFMA.
__global__ __launch_bounds__(256) void gemm_mfma(
    const float* __restrict__ A, const float* __restrict__ W,
    const float* __restrict__ bias, float* __restrict__ C)
{
    const int K = HID, N = VOC;
    __shared__ _Float16 As[128][40];   // 80B row stride: b128 frag reads 16B-aligned,
    __shared__ _Float16 Ws[128][40];   // 2-way bank alias only (free)
    int tid  = threadIdx.x;
    int wv   = tid >> 6;
    int lane = tid & 63;
    int wy = wv >> 1, wx = wv & 1;
    int quad = lane >> 4, l16 = lane & 15;
    int row0 = blockIdx.y << 7;
    int col0 = blockIdx.x << 7;

    v4f acc[4][4] = {};

    int sr = tid >> 1;             // staging row 0..127
    int sk = (tid & 1) << 4;       // k-half 0 / 16
    const float* ap = A + (size_t)(row0 + sr) * K + sk;
    const float* wp = W + (size_t)(col0 + sr) * K + sk;

    float4 a0 = *(const float4*)(ap);
    float4 a1 = *(const float4*)(ap + 4);
    float4 a2 = *(const float4*)(ap + 8);
    float4 a3 = *(const float4*)(ap + 12);
    float4 w0 = *(const float4*)(wp);
    float4 w1 = *(const float4*)(wp + 4);
    float4 w2 = *(const float4*)(wp + 8);
    float4 w3 = *(const float4*)(wp + 12);

    for (int k0 = 0; k0 < K; k0 += 32) {
        __syncthreads();           // prev iteration's LDS consumers done
        uint32_t* ad = (uint32_t*)&As[sr][sk];
        ad[0] = pack_pkrtz(a0.x, a0.y); ad[1] = pack_pkrtz(a0.z, a0.w);
        ad[2] = pack_pkrtz(a1.x, a1.y); ad[3] = pack_pkrtz(a1.z, a1.w);
        ad[4] = pack_pkrtz(a2.x, a2.y); ad[5] = pack_pkrtz(a2.z, a2.w);
        ad[6] = pack_pkrtz(a3.x, a3.y); ad[7] = pack_pkrtz(a3.z, a3.w);
        uint32_t* wd = (uint32_t*)&Ws[sr][sk];
        wd[0] = pack_pkrtz(w0.x, w0.y); wd[1] = pack_pkrtz(w0.z, w0.w);
        wd[2] = pack_pkrtz(w1.x, w1.y); wd[3] = pack_pkrtz(w1.z, w1.w);
        wd[4] = pack_pkrtz(w2.x, w2.y); wd[5] = pack_pkrtz(w2.z, w2.w);
        wd[6] = pack_pkrtz(w3.x, w3.y); wd[7] = pack_pkrtz(w3.z, w3.w);
        __syncthreads();           // LDS filled
        if (k0 + 32 < K) {         // prefetch next K-tile (consumed next iter)
            const float* apn = ap + k0 + 32;
            const float* wpn = wp + k0 + 32;
            a0 = *(const float4*)(apn);
            a1 = *(const float4*)(apn + 4);
            a2 = *(const float4*)(apn + 8);
            a3 = *(const float4*)(apn + 12);
            w0 = *(const float4*)(wpn);
            w1 = *(const float4*)(wpn + 4);
            w2 = *(const float4*)(wpn + 8);
            w3 = *(const float4*)(wpn + 12);
        }
        v8h af[4], bf[4];
        #pragma unroll
        for (int i = 0; i < 4; ++i)
            af[i] = *(const v8h*)&As[wy * 64 + i * 16 + l16][quad * 8];
        #pragma unroll
        for (int j = 0; j < 4; ++j)
            bf[j] = *(const v8h*)&Ws[wx * 64 + j * 16 + l16][quad * 8];
        #pragma unroll
        for (int i = 0; i < 4; ++i)
            #pragma unroll
            for (int j = 0; j < 4; ++j)
                acc[i][j] = __builtin_amdgcn_mfma_f32_16x16x32_f16(af[i], bf[j], acc[i][j], 0, 0, 0);
    }
    #pragma unroll
    for (int i = 0; i < 4; ++i) {
        #pragma unroll
        for (int j = 0; j < 4; ++j) {
            int ccol = col0 + wx * 64 + j * 16 + l16;
            float bb = bias[ccol];
            #pragma unroll
            for (int r = 0; r < 4; ++r) {
                int rrow = row0 + wy * 64 + i * 16 + quad * 4 + r;
                C[(size_t)rrow * N + ccol] = acc[i][j][r] + bb;
            }
        }
    }
}

// ---------------- E4[v4][c] = u8x4( round(exp(trans[4v4+k][c]) * 196) ) ----------------
__global__ __launch_bounds__(256) void e4_pack(
    const float* __restrict__ trans, uint32_t* __restrict__ E4)
{
    int idx = blockIdx.x * 256 + threadIdx.x;   // over 256*1024
    int v4 = idx >> 10, c = idx & 1023;
    uint32_t r = 0;
    #pragma unroll
    for (int k = 0; k < 4; ++k) {
        float e = __expf(trans[(size_t)(4 * v4 + k) * VOC + c]) * 196.f;
        uint32_t q = (uint32_t)__float2uint_rn(fminf(e, 255.f));
        r |= q << (8 * k);
    }
    E4[idx] = r;
}

// ---------------- persistent CRF scan v10: E in VGPRs + fin pipelining ----------------
// grid (16 bg, 16 cc), 512 thr = 8 waves. fin(t+1) loads issue right after step t's
// zstore -> L3 latency overlaps store-drain + barrier. Copy-through fin is pure
// register forwarding (finv = outv): no L3 load for finished batches.
__global__ __launch_bounds__(512) void crf_scan(
    const float* __restrict__ logits, float* __restrict__ Za, float* __restrict__ Zb,
    const uint32_t* __restrict__ E4, const int* __restrict__ lengths,
    unsigned int* __restrict__ cnt)
{
    __shared__ float Sred[8][64][3];   // [wave][col][batch], +1 pad
    __shared__ float Mred[8][2];       // half-wave chunk maxes per batch
    int tid  = threadIdx.x;
    int w    = tid >> 6;
    int lane = tid & 63;
    int h    = lane >> 5;              // staged batch half
    int li   = lane & 31;              // v4 slot within wave half
    int bg   = blockIdx.x;
    int cc   = blockIdx.y;
    int b0   = bg * 2;

    int len2[2];
    len2[0] = lengths[b0];
    len2[1] = lengths[b0 + 1];
    int lmax = max(len2[0], len2[1]);

    int c = (cc << 6) + lane;                                // own column
    const uint32_t* Ec = E4 + c + ((size_t)(w << 5) << 10);  // 32 rows, stride 1024

    uint32_t Ereg[32];                 // E slice resident for the whole scan
    #pragma unroll
    for (int j = 0; j < 32; ++j) Ereg[j] = Ec[(size_t)j << 10];

    // fin for t=1
    float finv = 0.f;
    if (tid < 128) {
        int b = b0 + w;
        finv = (1 < len2[w]) ? logits[(size_t)NB * VOC + (size_t)b * VOC + c]
                             : logits[(size_t)b * VOC + c];
    }

    const float* src = logits;         // Z0 = logits[t=0] (rows 0..31)
    for (int t = 1; t < TLEN; ++t) {
        float* dst = (t & 1) ? Za : Zb;
        if (t >= lmax) {               // uniform across this bg's 16 blocks
            if (src != Za && tid < 128) {
                int b = b0 + w;
                Za[(size_t)b * VOC + c] = zload(&src[(size_t)b * VOC + c]);
            }
            return;
        }
        // (A) staging: thread loads 4 v of its half's batch; half-wave max
        const float* zp = src + (size_t)(b0 + h) * VOC + (w << 7) + (li << 2);
        float2 za = zload2(zp);
        float2 zb = zload2(zp + 2);
        float m = fmaxf(fmaxf(za.x, za.y), fmaxf(zb.x, zb.y));
        #pragma unroll
        for (int off = 16; off; off >>= 1) m = fmaxf(m, __shfl_xor(m, off));
        if (li == 0) Mred[w][h] = m;
        uint32_t q0 = (uint32_t)__float2uint_rn(__expf(za.x - m) * 255.f);
        uint32_t q1 = (uint32_t)__float2uint_rn(__expf(za.y - m) * 255.f);
        uint32_t q2 = (uint32_t)__float2uint_rn(__expf(zb.x - m) * 255.f);
        uint32_t q3 = (uint32_t)__float2uint_rn(__expf(zb.y - m) * 255.f);
        uint32_t pp = q0 | (q1 << 8) | (q2 << 16) | (q3 << 24);

        // (C) compute: 32 v4-rows, E from registers; p lane->SGPR via readlane
        int a0a = 0, a0b = 0, a1a = 0, a1b = 0;
        #pragma unroll
        for (int j = 0; j < 32; j += 2) {
            uint32_t s00 = (uint32_t)__builtin_amdgcn_readlane((int)pp, j);
            uint32_t s10 = (uint32_t)__builtin_amdgcn_readlane((int)pp, j + 32);
            uint32_t s01 = (uint32_t)__builtin_amdgcn_readlane((int)pp, j + 1);
            uint32_t s11 = (uint32_t)__builtin_amdgcn_readlane((int)pp, j + 33);
            a0a = udot4(Ereg[j], s00, a0a);
            a1a = udot4(Ereg[j], s10, a1a);
            a0b = udot4(Ereg[j + 1], s01, a0b);
            a1b = udot4(Ereg[j + 1], s11, a1b);
        }
        Sred[w][lane][0] = (float)(a0a + a0b);
        Sred[w][lane][1] = (float)(a1a + a1b);
        __syncthreads();

        // (E) finalize + fin(t+1) prefetch
        if (tid < 128) {
            float M = Mred[0][w];
            #pragma unroll
            for (int ww = 1; ww < 8; ++ww) M = fmaxf(M, Mred[ww][w]);
            float S = 0.f;
            #pragma unroll
            for (int ww = 0; ww < 8; ++ww)
                S += __expf(Mred[ww][w] - M) * Sred[ww][lane][w];
            int b = b0 + w;
            float outv;
            if (t < len2[w]) outv = finv + M + __logf(S * (1.0f / (255.f * 196.f)));
            else             outv = finv;
            zstore(&dst[(size_t)b * VOC + c], outv);
            // prefetch finalize operand for t+1 (overlaps drain + barrier)
            int tn = t + 1;
            if (tn < len2[w]) finv = logits[((size_t)tn * NB + b) * VOC + c];
            else              finv = outv;      // copy-through: register forward
        }

        // (F) inter-block barrier among this bg's 16 blocks
        __syncthreads();               // drains vmcnt(0): Z stores visible
        if (tid == 0) {
            unsigned int* c16 = &cnt[t * 16 + bg];
            __hip_atomic_fetch_add(c16, 1u, __ATOMIC_RELAXED, __HIP_MEMORY_SCOPE_AGENT);
            while (__hip_atomic_load(c16, __ATOMIC_RELAXED, __HIP_MEMORY_SCOPE_AGENT) < 16u)
                __builtin_amdgcn_s_sleep(1);
        }
        __syncthreads();
        src = dst;
    }
}

// ---------------- epilogue v2: one block per batch, atomicAdd combine ----------------
__global__ __launch_bounds__(256) void crf_finish2(
    const float* __restrict__ Zfin, const float* __restrict__ logits,
    const float* __restrict__ trans, const int* __restrict__ targets,
    const int* __restrict__ lengths, float* __restrict__ out)
{
    __shared__ float redm[4], reds[4], reda[4];
    int b = blockIdx.x;
    int tid = threadIdx.x;
    int lane = tid & 63, wv = tid >> 6;
    const float* zr = Zfin + (size_t)b * VOC;

    float m = -1e30f;
    #pragma unroll
    for (int i = 0; i < 4; ++i) m = fmaxf(m, zr[tid + (i << 8)]);
    #pragma unroll
    for (int off = 32; off; off >>= 1) m = fmaxf(m, __shfl_xor(m, off));
    if (lane == 0) redm[wv] = m;
    __syncthreads();
    m = fmaxf(fmaxf(redm[0], redm[1]), fmaxf(redm[2], redm[3]));

    float s = 0.f;
    #pragma unroll
    for (int i = 0; i < 4; ++i) s += __expf(zr[tid + (i << 8)] - m);
    #pragma unroll
    for (int off = 32; off; off >>= 1) s += __shfl_xor(s, off);
    if (lane == 0) reds[wv] = s;

    // score: t = tid (256 threads cover all timesteps)
    int len = lengths[b];
    float acc = 0.f;
    int t = tid;
    if (t < len) {
        int tg = targets[t * NB + b];
        acc = logits[((size_t)t * NB + b) * VOC + tg];
        if (t >= 1) acc += trans[(size_t)targets[(t - 1) * NB + b] * VOC + tg];
    }
    #pragma unroll
    for (int off = 32; off; off >>= 1) acc += __shfl_xor(acc, off);
    if (lane == 0) reda[wv] = acc;
    __syncthreads();

    if (tid == 0) {
        float S = reds[0] + reds[1] + reds[2] + reds[3];
        float logZ = m + __logf(S);
        float score = reda[0] + reda[1] + reda[2] + reda[3];
        atomicAdd(out, (logZ - score) * (1.0f / NB));
    }
}

extern "C" void kernel_launch(void* const* d_in, const int* in_sizes, int n_in,
                              void* d_out, int out_size, void* d_ws, size_t ws_size,
                              hipStream_t stream)
{
    const float* enc   = (const float*)d_in[0];
    const float* W     = (const float*)d_in[1];
    const float* bias  = (const float*)d_in[2];
    const float* trans = (const float*)d_in[3];
    const int* targets = (const int*)d_in[4];
    const int* lengths = (const int*)d_in[5];
    float* out = (float*)d_out;

    // ws: logits 33.5MB | E4 1MB | Za 128KB | Zb 128KB | cnt 16KB
    float* ws     = (float*)d_ws;
    float* logits = ws;
    uint32_t* E4  = (uint32_t*)(logits + (size_t)TLEN * NB * VOC);
    float* Za     = (float*)(E4 + (size_t)(VOC / 4) * VOC);
    float* Zb     = Za + (size_t)NB * VOC;
    unsigned int* cnt = (unsigned int*)(Zb + (size_t)NB * VOC);

    (void)hipMemsetAsync(cnt, 0, TLEN * 16 * sizeof(unsigned int), stream);
    (void)hipMemsetAsync(out, 0, sizeof(float), stream);
    gemm_mfma<<<dim3(VOC / 128, TLEN * NB / 128), 256, 0, stream>>>(enc, W, bias, logits);
    e4_pack<<<dim3((VOC / 4) * VOC / 256), 256, 0, stream>>>(trans, E4);
    crf_scan<<<dim3(16, 16), 512, 0, stream>>>(logits, Za, Zb, E4, lengths, cnt);
    crf_finish2<<<NB, 256, 0, stream>>>(Za, logits, trans, targets, lengths, out);
}

// Round 14
// 626.915 us; speedup vs baseline: 10.0089x; 1.0613x over previous
//
#include <hip/hip_runtime.h>
#include <math.h>
#include <stdint.h>

#define TLEN 256
#define NB   32
#define HID  512
#define VOC  1024

typedef __attribute__((ext_vector_type(2))) _Float16 half2_t;
typedef __attribute__((ext_vector_type(2))) __fp16  pk16_t;
typedef __attribute__((ext_vector_type(8))) _Float16 v8h;
typedef __attribute__((ext_vector_type(4))) float    v4f;

// ---- device-coherent (agent-scope) Z accessors ----
__device__ __forceinline__ float zload(const float* p) {
    return __hip_atomic_load(p, __ATOMIC_RELAXED, __HIP_MEMORY_SCOPE_AGENT);
}
__device__ __forceinline__ float2 zload2(const float* p) {
    unsigned long long u = __hip_atomic_load((const unsigned long long*)p,
                                             __ATOMIC_RELAXED, __HIP_MEMORY_SCOPE_AGENT);
    union { unsigned long long u; float2 f; } c; c.u = u; return c.f;
}
__device__ __forceinline__ void zstore(float* p, float v) {
    __hip_atomic_store(p, v, __ATOMIC_RELAXED, __HIP_MEMORY_SCOPE_AGENT);
}
__device__ __forceinline__ uint32_t pack_pkrtz(float a, float b) {
    pk16_t h = __builtin_amdgcn_cvt_pkrtz(a, b);
    return __builtin_bit_cast(uint32_t, h);
}
__device__ __forceinline__ int udot4(uint32_t a, uint32_t b, int acc) {
#if __has_builtin(__builtin_amdgcn_udot4)
    return __builtin_amdgcn_udot4(a, b, acc, false);
#else
    return acc + (int)((a & 255u) * (b & 255u))
               + (int)(((a >> 8) & 255u) * ((b >> 8) & 255u))
               + (int)(((a >> 16) & 255u) * ((b >> 16) & 255u))
               + (int)((a >> 24) * (b >> 24));
#endif
}

// ---------------- GEMM: MFMA f16 16x16x32, 128x128 tile, reg prefetch ----------------
__global__ __launch_bounds__(256) void gemm_mfma(
    const float* __restrict__ A, const float* __restrict__ W,
    const float* __restrict__ bias, float* __restrict__ C)
{
    const int K = HID, N = VOC;
    __shared__ _Float16 As[128][40];
    __shared__ _Float16 Ws[128][40];
    int tid  = threadIdx.x;
    int wv   = tid >> 6;
    int lane = tid & 63;
    int wy = wv >> 1, wx = wv & 1;
    int quad = lane >> 4, l16 = lane & 15;
    int row0 = blockIdx.y << 7;
    int col0 = blockIdx.x << 7;

    v4f acc[4][4] = {};

    int sr = tid >> 1;
    int sk = (tid & 1) << 4;
    const float* ap = A + (size_t)(row0 + sr) * K + sk;
    const float* wp = W + (size_t)(col0 + sr) * K + sk;

    float4 a0 = *(const float4*)(ap);
    float4 a1 = *(const float4*)(ap + 4);
    float4 a2 = *(const float4*)(ap + 8);
    float4 a3 = *(const float4*)(ap + 12);
    float4 w0 = *(const float4*)(wp);
    float4 w1 = *(const float4*)(wp + 4);
    float4 w2 = *(const float4*)(wp + 8);
    float4 w3 = *(const float4*)(wp + 12);

    for (int k0 = 0; k0 < K; k0 += 32) {
        __syncthreads();
        uint32_t* ad = (uint32_t*)&As[sr][sk];
        ad[0] = pack_pkrtz(a0.x, a0.y); ad[1] = pack_pkrtz(a0.z, a0.w);
        ad[2] = pack_pkrtz(a1.x, a1.y); ad[3] = pack_pkrtz(a1.z, a1.w);
        ad[4] = pack_pkrtz(a2.x, a2.y); ad[5] = pack_pkrtz(a2.z, a2.w);
        ad[6] = pack_pkrtz(a3.x, a3.y); ad[7] = pack_pkrtz(a3.z, a3.w);
        uint32_t* wd = (uint32_t*)&Ws[sr][sk];
        wd[0] = pack_pkrtz(w0.x, w0.y); wd[1] = pack_pkrtz(w0.z, w0.w);
        wd[2] = pack_pkrtz(w1.x, w1.y); wd[3] = pack_pkrtz(w1.z, w1.w);
        wd[4] = pack_pkrtz(w2.x, w2.y); wd[5] = pack_pkrtz(w2.z, w2.w);
        wd[6] = pack_pkrtz(w3.x, w3.y); wd[7] = pack_pkrtz(w3.z, w3.w);
        __syncthreads();
        if (k0 + 32 < K) {
            const float* apn = ap + k0 + 32;
            const float* wpn = wp + k0 + 32;
            a0 = *(const float4*)(apn);
            a1 = *(const float4*)(apn + 4);
            a2 = *(const float4*)(apn + 8);
            a3 = *(const float4*)(apn + 12);
            w0 = *(const float4*)(wpn);
            w1 = *(const float4*)(wpn + 4);
            w2 = *(const float4*)(wpn + 8);
            w3 = *(const float4*)(wpn + 12);
        }
        v8h af[4], bf[4];
        #pragma unroll
        for (int i = 0; i < 4; ++i)
            af[i] = *(const v8h*)&As[wy * 64 + i * 16 + l16][quad * 8];
        #pragma unroll
        for (int j = 0; j < 4; ++j)
            bf[j] = *(const v8h*)&Ws[wx * 64 + j * 16 + l16][quad * 8];
        #pragma unroll
        for (int i = 0; i < 4; ++i)
            #pragma unroll
            for (int j = 0; j < 4; ++j)
                acc[i][j] = __builtin_amdgcn_mfma_f32_16x16x32_f16(af[i], bf[j], acc[i][j], 0, 0, 0);
    }
    #pragma unroll
    for (int i = 0; i < 4; ++i) {
        #pragma unroll
        for (int j = 0; j < 4; ++j) {
            int ccol = col0 + wx * 64 + j * 16 + l16;
            float bb = bias[ccol];
            #pragma unroll
            for (int r = 0; r < 4; ++r) {
                int rrow = row0 + wy * 64 + i * 16 + quad * 4 + r;
                C[(size_t)rrow * N + ccol] = acc[i][j][r] + bb;
            }
        }
    }
}

// ---------------- persistent CRF scan v11 ----------------
// grid (16 bg, 16 cc), 512 thr = 8 waves. Changes vs v10:
//  - E slice computed in-kernel from trans (drops e4_pack kernel).
//  - Barrier: per-bg MONOTONIC padded counter (64B apart, same line every step ->
//    L3-hot, no cross-bg false sharing); target 16*t; fetch_add return value lets
//    the LAST arriver skip the poll read (removes 1 L3 RT from the critical chain).
__global__ __launch_bounds__(512) void crf_scan(
    const float* __restrict__ logits, float* __restrict__ Za, float* __restrict__ Zb,
    const float* __restrict__ trans, const int* __restrict__ lengths,
    unsigned int* __restrict__ cnt)
{
    __shared__ float Sred[8][64][3];   // [wave][col][batch], +1 pad
    __shared__ float Mred[8][2];       // half-wave chunk maxes per batch
    int tid  = threadIdx.x;
    int w    = tid >> 6;
    int lane = tid & 63;
    int h    = lane >> 5;              // staged batch half
    int li   = lane & 31;              // v4 slot within wave half
    int bg   = blockIdx.x;
    int cc   = blockIdx.y;
    int b0   = bg * 2;

    int len2[2];
    len2[0] = lengths[b0];
    len2[1] = lengths[b0 + 1];
    int lmax = max(len2[0], len2[1]);

    int c = (cc << 6) + lane;          // own column

    // E slice resident in VGPRs: Ereg[j] = u8x4 of exp(trans[128w+4j+k][c])*196
    uint32_t Ereg[32];
    {
        const float* tc = trans + c;
        #pragma unroll
        for (int j = 0; j < 32; ++j) {
            int v0 = (w << 7) + (j << 2);
            float e0 = __expf(tc[(size_t)(v0 + 0) << 10]) * 196.f;
            float e1 = __expf(tc[(size_t)(v0 + 1) << 10]) * 196.f;
            float e2 = __expf(tc[(size_t)(v0 + 2) << 10]) * 196.f;
            float e3 = __expf(tc[(size_t)(v0 + 3) << 10]) * 196.f;
            uint32_t q0 = (uint32_t)__float2uint_rn(fminf(e0, 255.f));
            uint32_t q1 = (uint32_t)__float2uint_rn(fminf(e1, 255.f));
            uint32_t q2 = (uint32_t)__float2uint_rn(fminf(e2, 255.f));
            uint32_t q3 = (uint32_t)__float2uint_rn(fminf(e3, 255.f));
            Ereg[j] = q0 | (q1 << 8) | (q2 << 16) | (q3 << 24);
        }
    }

    // fin for t=1
    float finv = 0.f;
    if (tid < 128) {
        int b = b0 + w;
        finv = (1 < len2[w]) ? logits[(size_t)NB * VOC + (size_t)b * VOC + c]
                             : logits[(size_t)b * VOC + c];
    }

    unsigned int* cbg = &cnt[bg << 4];  // padded: 64B per bg, monotonic

    const float* src = logits;          // Z0 = logits[t=0] (rows 0..31)
    for (int t = 1; t < TLEN; ++t) {
        float* dst = (t & 1) ? Za : Zb;
        if (t >= lmax) {                // uniform across this bg's 16 blocks
            if (src != Za && tid < 128) {
                int b = b0 + w;
                Za[(size_t)b * VOC + c] = zload(&src[(size_t)b * VOC + c]);
            }
            return;
        }
        // (A) staging: thread loads 4 v of its half's batch; half-wave max
        const float* zp = src + (size_t)(b0 + h) * VOC + (w << 7) + (li << 2);
        float2 za = zload2(zp);
        float2 zb = zload2(zp + 2);
        float m = fmaxf(fmaxf(za.x, za.y), fmaxf(zb.x, zb.y));
        #pragma unroll
        for (int off = 16; off; off >>= 1) m = fmaxf(m, __shfl_xor(m, off));
        if (li == 0) Mred[w][h] = m;
        uint32_t q0 = (uint32_t)__float2uint_rn(__expf(za.x - m) * 255.f);
        uint32_t q1 = (uint32_t)__float2uint_rn(__expf(za.y - m) * 255.f);
        uint32_t q2 = (uint32_t)__float2uint_rn(__expf(zb.x - m) * 255.f);
        uint32_t q3 = (uint32_t)__float2uint_rn(__expf(zb.y - m) * 255.f);
        uint32_t pp = q0 | (q1 << 8) | (q2 << 16) | (q3 << 24);

        // (C) compute: 32 v4-rows, E from registers; p lane->SGPR via readlane
        int a0a = 0, a0b = 0, a1a = 0, a1b = 0;
        #pragma unroll
        for (int j = 0; j < 32; j += 2) {
            uint32_t s00 = (uint32_t)__builtin_amdgcn_readlane((int)pp, j);
            uint32_t s10 = (uint32_t)__builtin_amdgcn_readlane((int)pp, j + 32);
            uint32_t s01 = (uint32_t)__builtin_amdgcn_readlane((int)pp, j + 1);
            uint32_t s11 = (uint32_t)__builtin_amdgcn_readlane((int)pp, j + 33);
            a0a = udot4(Ereg[j], s00, a0a);
            a1a = udot4(Ereg[j], s10, a1a);
            a0b = udot4(Ereg[j + 1], s01, a0b);
            a1b = udot4(Ereg[j + 1], s11, a1b);
        }
        Sred[w][lane][0] = (float)(a0a + a0b);
        Sred[w][lane][1] = (float)(a1a + a1b);
        __syncthreads();

        // (E) finalize + fin(t+1) prefetch
        if (tid < 128) {
            float M = Mred[0][w];
            #pragma unroll
            for (int ww = 1; ww < 8; ++ww) M = fmaxf(M, Mred[ww][w]);
            float S = 0.f;
            #pragma unroll
            for (int ww = 0; ww < 8; ++ww)
                S += __expf(Mred[ww][w] - M) * Sred[ww][lane][w];
            int b = b0 + w;
            float outv;
            if (t < len2[w]) outv = finv + M + __logf(S * (1.0f / (255.f * 196.f)));
            else             outv = finv;
            zstore(&dst[(size_t)b * VOC + c], outv);
            int tn = t + 1;
            if (tn < len2[w]) finv = logits[((size_t)tn * NB + b) * VOC + c];
            else              finv = outv;      // copy-through: register forward
        }

        // (F) inter-block barrier: monotonic counter, target 16*t; last skips poll
        __syncthreads();               // drains vmcnt(0): Z stores visible
        if (tid == 0) {
            unsigned int tgt = (unsigned int)(t << 4);
            unsigned int old = __hip_atomic_fetch_add(cbg, 1u, __ATOMIC_RELAXED,
                                                      __HIP_MEMORY_SCOPE_AGENT);
            if (old + 1u != tgt) {
                while (__hip_atomic_load(cbg, __ATOMIC_RELAXED,
                                         __HIP_MEMORY_SCOPE_AGENT) < tgt)
                    __builtin_amdgcn_s_sleep(1);
            }
        }
        __syncthreads();
        src = dst;
    }
}

// ---------------- epilogue: one block per batch, atomicAdd combine ----------------
__global__ __launch_bounds__(256) void crf_finish2(
    const float* __restrict__ Zfin, const float* __restrict__ logits,
    const float* __restrict__ trans, const int* __restrict__ targets,
    const int* __restrict__ lengths, float* __restrict__ out)
{
    __shared__ float redm[4], reds[4], reda[4];
    int b = blockIdx.x;
    int tid = threadIdx.x;
    int lane = tid & 63, wv = tid >> 6;
    const float* zr = Zfin + (size_t)b * VOC;

    float m = -1e30f;
    #pragma unroll
    for (int i = 0; i < 4; ++i) m = fmaxf(m, zr[tid + (i << 8)]);
    #pragma unroll
    for (int off = 32; off; off >>= 1) m = fmaxf(m, __shfl_xor(m, off));
    if (lane == 0) redm[wv] = m;
    __syncthreads();
    m = fmaxf(fmaxf(redm[0], redm[1]), fmaxf(redm[2], redm[3]));

    float s = 0.f;
    #pragma unroll
    for (int i = 0; i < 4; ++i) s += __expf(zr[tid + (i << 8)] - m);
    #pragma unroll
    for (int off = 32; off; off >>= 1) s += __shfl_xor(s, off);
    if (lane == 0) reds[wv] = s;

    int len = lengths[b];
    float acc = 0.f;
    int t = tid;
    if (t < len) {
        int tg = targets[t * NB + b];
        acc = logits[((size_t)t * NB + b) * VOC + tg];
        if (t >= 1) acc += trans[(size_t)targets[(t - 1) * NB + b] * VOC + tg];
    }
    #pragma unroll
    for (int off = 32; off; off >>= 1) acc += __shfl_xor(acc, off);
    if (lane == 0) reda[wv] = acc;
    __syncthreads();

    if (tid == 0) {
        float S = reds[0] + reds[1] + reds[2] + reds[3];
        float logZ = m + __logf(S);
        float score = reda[0] + reda[1] + reda[2] + reda[3];
        atomicAdd(out, (logZ - score) * (1.0f / NB));
    }
}

extern "C" void kernel_launch(void* const* d_in, const int* in_sizes, int n_in,
                              void* d_out, int out_size, void* d_ws, size_t ws_size,
                              hipStream_t stream)
{
    const float* enc   = (const float*)d_in[0];
    const float* W     = (const float*)d_in[1];
    const float* bias  = (const float*)d_in[2];
    const float* trans = (const float*)d_in[3];
    const int* targets = (const int*)d_in[4];
    const int* lengths = (const int*)d_in[5];
    float* out = (float*)d_out;

    // ws: logits 33.5MB | Za 128KB | Zb 128KB | cnt 1KB (16 bgs x 64B)
    float* ws     = (float*)d_ws;
    float* logits = ws;
    float* Za     = logits + (size_t)TLEN * NB * VOC;
    float* Zb     = Za + (size_t)NB * VOC;
    unsigned int* cnt = (unsigned int*)(Zb + (size_t)NB * VOC);

    (void)hipMemsetAsync(cnt, 0, 16 * 16 * sizeof(unsigned int), stream);
    (void)hipMemsetAsync(out, 0, sizeof(float), stream);
    gemm_mfma<<<dim3(VOC / 128, TLEN * NB / 128), 256, 0, stream>>>(enc, W, bias, logits);
    crf_scan<<<dim3(16, 16), 512, 0, stream>>>(logits, Za, Zb, trans, lengths, cnt);
    crf_finish2<<<NB, 256, 0, stream>>>(Za, logits, trans, targets, lengths, out);
}